// Round 9
// baseline (144.090 us; speedup 1.0000x reference)
//
#include <hip/hip_runtime.h>
#include <hip/hip_bf16.h>

typedef short bf16x8 __attribute__((ext_vector_type(8)));   // 8 bf16 (4 VGPRs)
typedef float f32x4  __attribute__((ext_vector_type(4)));
typedef unsigned short u16;
typedef unsigned int u32;

#define MFMA16(a, b, c) __builtin_amdgcn_mfma_f32_16x16x32_bf16((a), (b), (c), 0, 0, 0)

static __device__ __forceinline__ u16 f2b(float f) {
  __hip_bfloat16 h = __float2bfloat16(f);   // RNE (prep only)
  return __builtin_bit_cast(u16, h);
}
// HW packed convert: dst.lo = bf16(a), dst.hi = bf16(b)  (RNE)
static __device__ __forceinline__ u32 cvtpk(float a, float b) {
  u32 r;
  asm("v_cvt_pk_bf16_f32 %0, %1, %2" : "=v"(r) : "v"(a), "v"(b));
  return r;
}
static __device__ __forceinline__ float blo(u32 u) {
  return __builtin_bit_cast(float, u << 16);
}
static __device__ __forceinline__ float bhi(u32 u) {
  return __builtin_bit_cast(float, u & 0xffff0000u);
}
static __device__ __forceinline__ float fexp2(float x) {
#if __has_builtin(__builtin_amdgcn_exp2f)
  return __builtin_amdgcn_exp2f(x);   // raw v_exp_f32 (2^x)
#else
  return exp2f(x);
#endif
}

union FragU { uint4 u; bf16x8 v; };

// g-group shuffle: source lane (c,gs) holds (tile t: x=16t+4*gs+r, y=c) packed
// as uint2 {pk(r0,r1), pk(r2,r3)} for tiles lo (x 0..15) and hi (x 16..31).
// Returns frag: lane (c,g) elem e = M[x=8g+e][y=c]  (e=0..7).
static __device__ __forceinline__ bf16x8 shufx(uint2 lo, uint2 hi,
                                               int sA4, int sB4, bool uh) {
  u32 l0 = (u32)__builtin_amdgcn_ds_bpermute(sA4, (int)lo.x);
  u32 l1 = (u32)__builtin_amdgcn_ds_bpermute(sA4, (int)lo.y);
  u32 h0 = (u32)__builtin_amdgcn_ds_bpermute(sA4, (int)hi.x);
  u32 h1 = (u32)__builtin_amdgcn_ds_bpermute(sA4, (int)hi.y);
  u32 l2 = (u32)__builtin_amdgcn_ds_bpermute(sB4, (int)lo.x);
  u32 l3 = (u32)__builtin_amdgcn_ds_bpermute(sB4, (int)lo.y);
  u32 h2 = (u32)__builtin_amdgcn_ds_bpermute(sB4, (int)hi.x);
  u32 h3 = (u32)__builtin_amdgcn_ds_bpermute(sB4, (int)hi.y);
  FragU f;
  f.u.x = uh ? h0 : l0;  f.u.y = uh ? h1 : l1;
  f.u.z = uh ? h2 : l2;  f.u.w = uh ? h3 : l3;
  return f.v;
}

// ---------------------------------------------------------------------------
// Prep: b 0..127:   wqkT[o][i] = wqkv[i][o] (Q rows scaled by 32^-0.5*log2e)
//       b 128..191: wvB  frag-packed Wv[k][col]                       65536 u16
//       b 192..255: woutB frag-packed Wout[k][col]                    65536 u16
//       b 256..259: biasQ[i][j] = bias(query i, key j)*log2e, bf16    4096 u16
__global__ void prep(const float* __restrict__ wqkv, const float* __restrict__ wout,
                     const float* __restrict__ pos, u16* __restrict__ wqkT,
                     u16* __restrict__ wvB, u16* __restrict__ woutB,
                     u16* __restrict__ biasQ) {
  const int b = blockIdx.x, t = threadIdx.x;
  const float s2 = 0.25503486f;       // 32^-0.5 * log2(e) folded into Wq
  const float l2e = 1.4426950408889634f;
  if (b < 128) {
    int e0 = b * 1024 + t * 4;
#pragma unroll
    for (int i = 0; i < 4; ++i) {
      int e = e0 + i, o = e >> 8, ii = e & 255;
      float v = wqkv[(size_t)ii * 768 + o];
      wqkT[e] = f2b(o < 256 ? v * s2 : v);
    }
  } else if (b < 192) {
    int e0 = (b - 128) * 1024 + t * 4;
#pragma unroll
    for (int i = 0; i < 4; ++i) {
      int e = e0 + i, frag = e >> 9, w = e & 511, lane = w >> 3, ee = w & 7;
      int k8 = frag >> 4, np = frag & 15;
      int k = k8 * 32 + ((lane >> 4) << 3) + ee;
      int col = 512 + np * 16 + (lane & 15);
      wvB[e] = f2b(wqkv[(size_t)k * 768 + col]);
    }
  } else if (b < 256) {
    int e0 = (b - 192) * 1024 + t * 4;
#pragma unroll
    for (int i = 0; i < 4; ++i) {
      int e = e0 + i, frag = e >> 9, w = e & 511, lane = w >> 3, ee = w & 7;
      int k8 = frag >> 4, np = frag & 15;
      int k = k8 * 32 + ((lane >> 4) << 3) + ee;
      int col = np * 16 + (lane & 15);
      woutB[e] = f2b(wout[(size_t)k * 256 + col]);
    }
  } else {
    int e0 = (b - 256) * 1024 + t * 4;
#pragma unroll
    for (int i = 0; i < 4; ++i) {
      int e = e0 + i, iq = e >> 6, jk = e & 63;
      int ix = iq >> 3, iy = iq & 7, jx = jk >> 3, jy = jk & 7;
      biasQ[e] = f2b(l2e * pos[(jx - ix + 7) * 15 + (jy - iy + 7)]);
    }
  }
}

// ---------------------------------------------------------------------------
// Fused window attention: 1 block = 1 window, 8 waves, wave = head.
// Merged QK pass; V^T through wave-private VTs (no barrier); bias (log2-scaled)
// as MFMA C-input; exp2 softmax without max-pass; per-tqt AO store into the
// dead X region (barrier moved before the attention loop). 3 barriers.
__global__ __launch_bounds__(512, 4)
void winattn(const float* __restrict__ x,
             const u16* __restrict__ wqkT,    // [512][256] bf16 (Q rows scaled)
             const u16* __restrict__ wvB,     // frag-packed [8][16][64][8]
             const u16* __restrict__ woutB,   // frag-packed [8][16][64][8]
             const float* __restrict__ b_out, // [256] f32
             const u16* __restrict__ biasQ,   // [64][64] bf16, query-major
             float* __restrict__ out) {
  __shared__ u16 Xs[64][264];    // bf16 X tile; AO overlay after B2
  __shared__ u16 VTs[256][72];   // V^T[inner][tok], wave-private rows
  __shared__ u16 Bs[64][68];     // bias, query-major bf16 (log2e-scaled)

  const int tid  = threadIdx.x;
  const int lane = tid & 63;
  const int h    = tid >> 6;     // wave = head, 0..7
  const int c    = lane & 15;
  const int g    = lane >> 4;

  const int win = blockIdx.x;
  const int img = win >> 8;
  const int wid = win & 255;
  const int py0 = (wid >> 4) << 3;
  const int px0 = (wid & 15) << 3;
  const size_t imgbase = (size_t)img * (128 * 128);

  const f32x4 fz = {0.f, 0.f, 0.f, 0.f};

  // ---- stage X (f32 -> bf16, cvt_pk, b128 LDS writes) and bias table
#pragma unroll
  for (int it = 0; it < 4; ++it) {
    int ch = tid + it * 512;            // 2048 = 64 rows x 32 chunks of 8
    int row = ch >> 5, c8 = (ch & 31) << 3;
    int py = py0 + (row >> 3), px = px0 + (row & 7);
    const float* src = x + ((size_t)(imgbase + py * 128 + px)) * 256 + c8;
    const float4 v0 = *reinterpret_cast<const float4*>(src);
    const float4 v1 = *reinterpret_cast<const float4*>(src + 4);
    uint4 pk{cvtpk(v0.x, v0.y), cvtpk(v0.z, v0.w),
             cvtpk(v1.x, v1.y), cvtpk(v1.z, v1.w)};
    *reinterpret_cast<uint4*>(&Xs[row][c8]) = pk;
  }
  {   // 4096 u16 bias: each thread two ushort4
    int row = tid >> 3, c0 = (tid & 7) * 8;
    *reinterpret_cast<ushort4*>(&Bs[row][c0]) =
        *reinterpret_cast<const ushort4*>(biasQ + row * 64 + c0);
    *reinterpret_cast<ushort4*>(&Bs[row][c0 + 4]) =
        *reinterpret_cast<const ushort4*>(biasQ + row * 64 + c0 + 4);
  }
  __syncthreads();                      // B1

  // bpermute lane addresses (loop-invariant)
  const int sA4 = (c + 16 * ((2 * g) & 3)) * 4;
  const int sB4 = (c + 16 * ((2 * g + 1) & 3)) * 4;
  const bool uh = g >= 2;

  const int hq = h * 32, hk = 256 + h * 32;

  // ---- merged QK pass: Q^T = Wq^T X^T and K^T = Wk^T X^T share X frags
  bf16x8 qf[4], kf[4];
  {
    f32x4 aq0[4], aq1[4], ak0[4], ak1[4];
#pragma unroll
    for (int nt = 0; nt < 4; ++nt) {
      aq0[nt] = fz; aq1[nt] = fz; ak0[nt] = fz; ak1[nt] = fz;
    }
#pragma unroll 2
    for (int k8 = 0; k8 < 8; ++k8) {
      bf16x8 xb[4];
#pragma unroll
      for (int nt = 0; nt < 4; ++nt)
        xb[nt] = *reinterpret_cast<const bf16x8*>(&Xs[nt * 16 + c][k8 * 32 + g * 8]);
      const bf16x8 wq0 = *reinterpret_cast<const bf16x8*>(
          wqkT + (size_t)(hq + c) * 256 + k8 * 32 + g * 8);
      const bf16x8 wq1 = *reinterpret_cast<const bf16x8*>(
          wqkT + (size_t)(hq + 16 + c) * 256 + k8 * 32 + g * 8);
      const bf16x8 wk0 = *reinterpret_cast<const bf16x8*>(
          wqkT + (size_t)(hk + c) * 256 + k8 * 32 + g * 8);
      const bf16x8 wk1 = *reinterpret_cast<const bf16x8*>(
          wqkT + (size_t)(hk + 16 + c) * 256 + k8 * 32 + g * 8);
#pragma unroll
      for (int nt = 0; nt < 4; ++nt) {
        aq0[nt] = MFMA16(wq0, xb[nt], aq0[nt]);
        aq1[nt] = MFMA16(wq1, xb[nt], aq1[nt]);
        ak0[nt] = MFMA16(wk0, xb[nt], ak0[nt]);
        ak1[nt] = MFMA16(wk1, xb[nt], ak1[nt]);
      }
    }
#pragma unroll
    for (int t4 = 0; t4 < 4; ++t4) {
      uint2 qlo{cvtpk(aq0[t4][0], aq0[t4][1]), cvtpk(aq0[t4][2], aq0[t4][3])};
      uint2 qhi{cvtpk(aq1[t4][0], aq1[t4][1]), cvtpk(aq1[t4][2], aq1[t4][3])};
      qf[t4] = shufx(qlo, qhi, sA4, sB4, uh);
      uint2 klo{cvtpk(ak0[t4][0], ak0[t4][1]), cvtpk(ak0[t4][2], ak0[t4][3])};
      uint2 khi{cvtpk(ak1[t4][0], ak1[t4][1]), cvtpk(ak1[t4][2], ak1[t4][3])};
      kf[t4] = shufx(klo, khi, sA4, sB4, uh);
    }
  }

  // ---- V pass: V = X Wv; D lane (c,g)[r] = V[tok=16mt+4g+r][dim=16(2h+j)+c]
  // -> write V^T straight to LDS (own-head rows only; no barrier needed)
  {
    f32x4 av[4][2];
#pragma unroll
    for (int mt = 0; mt < 4; ++mt)
#pragma unroll
      for (int j = 0; j < 2; ++j) av[mt][j] = fz;
#pragma unroll 1
    for (int k8 = 0; k8 < 8; ++k8) {
      bf16x8 xb[4];
#pragma unroll
      for (int mt = 0; mt < 4; ++mt)
        xb[mt] = *reinterpret_cast<const bf16x8*>(&Xs[mt * 16 + c][k8 * 32 + g * 8]);
      bf16x8 bv[2];
#pragma unroll
      for (int j = 0; j < 2; ++j)
        bv[j] = *reinterpret_cast<const bf16x8*>(
            wvB + (size_t)((k8 * 16 + 2 * h + j) * 64 + lane) * 8);
#pragma unroll
      for (int mt = 0; mt < 4; ++mt)
#pragma unroll
        for (int j = 0; j < 2; ++j)
          av[mt][j] = MFMA16(xb[mt], bv[j], av[mt][j]);
    }
#pragma unroll
    for (int j = 0; j < 2; ++j)
#pragma unroll
      for (int mt = 0; mt < 4; ++mt) {
        uint2 pk{cvtpk(av[mt][j][0], av[mt][j][1]),
                 cvtpk(av[mt][j][2], av[mt][j][3])};
        *reinterpret_cast<uint2*>(&VTs[(2 * h + j) * 16 + c][mt * 16 + 4 * g]) = pk;
      }
  }

  // vf[kk][dt]: A-frags for PV, wave-private readback (same-wave RAW ordering)
  bf16x8 vf[2][2];
#pragma unroll
  for (int kk = 0; kk < 2; ++kk)
#pragma unroll
    for (int dt = 0; dt < 2; ++dt)
      vf[kk][dt] = *reinterpret_cast<const bf16x8*>(
          &VTs[h * 32 + dt * 16 + c][kk * 32 + g * 8]);

  __syncthreads();   // B2: all X reads done; Xs becomes the AO buffer

  // ---- attention, tqt-split: S^T (bias as C-input, log2 units) -> exp2
  // (no max-pass: scores bounded) -> PV -> normalize -> per-tqt AO store
#pragma unroll
  for (int tqt = 0; tqt < 4; ++tqt) {
    uint2 bb[4];
#pragma unroll
    for (int tkt = 0; tkt < 4; ++tkt)
      bb[tkt] = *reinterpret_cast<const uint2*>(&Bs[tqt * 16 + c][tkt * 16 + 4 * g]);
    f32x4 stq[4];
#pragma unroll
    for (int tkt = 0; tkt < 4; ++tkt) {
      const f32x4 bf = {blo(bb[tkt].x), bhi(bb[tkt].x),
                        blo(bb[tkt].y), bhi(bb[tkt].y)};
      stq[tkt] = MFMA16(kf[tkt], qf[tqt], bf);   // bias added free via C
    }
#pragma unroll
    for (int tkt = 0; tkt < 4; ++tkt)
#pragma unroll
      for (int r = 0; r < 4; ++r)
        stq[tkt][r] = fexp2(stq[tkt][r]);        // raw v_exp_f32
    float s0 = (stq[0][0] + stq[0][1]) + (stq[0][2] + stq[0][3]);
    float s1 = (stq[1][0] + stq[1][1]) + (stq[1][2] + stq[1][3]);
    float s2 = (stq[2][0] + stq[2][1]) + (stq[2][2] + stq[2][3]);
    float s3 = (stq[3][0] + stq[3][1]) + (stq[3][2] + stq[3][3]);
    float sum = (s0 + s1) + (s2 + s3);
    sum += __shfl_xor(sum, 16);
    sum += __shfl_xor(sum, 32);
    const float rs = __builtin_amdgcn_rcpf(sum);   // used post-PV only

    f32x4 o0 = fz, o1 = fz;
#pragma unroll
    for (int kk = 0; kk < 2; ++kk) {   // P unnormalized into pf
      uint2 lo{cvtpk(stq[2 * kk][0], stq[2 * kk][1]),
               cvtpk(stq[2 * kk][2], stq[2 * kk][3])};
      uint2 hi{cvtpk(stq[2 * kk + 1][0], stq[2 * kk + 1][1]),
               cvtpk(stq[2 * kk + 1][2], stq[2 * kk + 1][3])};
      bf16x8 pf = shufx(lo, hi, sA4, sB4, uh);
      o0 = MFMA16(vf[kk][0], pf, o0);
      o1 = MFMA16(vf[kk][1], pf, o1);
    }
    // rs lives in exactly this lane (tq = c + 16*tqt both sides).
    // AO[tq][h*32 + 16*dt + 4g + r] written immediately (X dead after B2).
    *reinterpret_cast<uint2*>(&Xs[c + 16 * tqt][h * 32 + 4 * g]) =
        uint2{cvtpk(o0[0] * rs, o0[1] * rs), cvtpk(o0[2] * rs, o0[3] * rs)};
    *reinterpret_cast<uint2*>(&Xs[c + 16 * tqt][h * 32 + 16 + 4 * g]) =
        uint2{cvtpk(o1[0] * rs, o1[1] * rs), cvtpk(o1[2] * rs, o1[3] * rs)};
  }
  __syncthreads();                      // B3

  // ---- projection: Y = AO Wout + b_out (A=AO frag from LDS, B=woutB frag)
  f32x4 yc[4][2];
#pragma unroll
  for (int mt = 0; mt < 4; ++mt)
#pragma unroll
    for (int jj = 0; jj < 2; ++jj) yc[mt][jj] = fz;
#pragma unroll 2
  for (int k8 = 0; k8 < 8; ++k8) {
    bf16x8 af[4];
#pragma unroll
    for (int mt = 0; mt < 4; ++mt)
      af[mt] = *reinterpret_cast<const bf16x8*>(&Xs[mt * 16 + c][k8 * 32 + g * 8]);
    bf16x8 bw[2];
#pragma unroll
    for (int jj = 0; jj < 2; ++jj) {
      int nt = h * 2 + jj;
      bw[jj] = *reinterpret_cast<const bf16x8*>(
          woutB + (size_t)((k8 * 16 + nt) * 64 + lane) * 8);
    }
#pragma unroll
    for (int mt = 0; mt < 4; ++mt)
#pragma unroll
      for (int jj = 0; jj < 2; ++jj)
        yc[mt][jj] = MFMA16(af[mt], bw[jj], yc[mt][jj]);
  }
#pragma unroll
  for (int jj = 0; jj < 2; ++jj) {
    const int nt = h * 2 + jj;
    const float bo = b_out[nt * 16 + c];
#pragma unroll
    for (int mt = 0; mt < 4; ++mt)
#pragma unroll
      for (int r = 0; r < 4; ++r) {
        int row = mt * 16 + g * 4 + r;
        int py = py0 + (row >> 3), px = px0 + (row & 7);
        out[((size_t)(imgbase + py * 128 + px)) * 256 + nt * 16 + c] =
            yc[mt][jj][r] + bo;
      }
  }
}

// ---------------------------------------------------------------------------
extern "C" void kernel_launch(void* const* d_in, const int* in_sizes, int n_in,
                              void* d_out, int out_size, void* d_ws, size_t ws_size,
                              hipStream_t stream) {
  const float* x    = (const float*)d_in[0];   // [2,4,128,128,256] f32
  const float* wqkv = (const float*)d_in[1];   // [256,768] f32
  const float* wout = (const float*)d_in[2];   // [256,256] f32
  const float* bout = (const float*)d_in[3];   // [256] f32
  const float* pos  = (const float*)d_in[4];   // [15,15] f32
  float* out = (float*)d_out;

  u16* wqkT  = (u16*)d_ws;                     // 512*256 u16 = 256 KiB
  u16* wvB   = wqkT + 512 * 256;               // 65536 u16 = 128 KiB
  u16* woutB = wvB + 65536;                    // 65536 u16 = 128 KiB
  u16* biasQ = woutB + 65536;                  // 4096 u16 = 8 KiB

  prep<<<260, 256, 0, stream>>>(wqkv, wout, pos, wqkT, wvB, woutB, biasQ);
  winattn<<<2048, 512, 0, stream>>>(x, wqkT, wvB, woutB, bout, biasQ, out);
}

// Round 11
// 138.379 us; speedup vs baseline: 1.0413x; 1.0413x over previous
//
#include <hip/hip_runtime.h>
#include <hip/hip_bf16.h>

typedef short bf16x8 __attribute__((ext_vector_type(8)));   // 8 bf16 (4 VGPRs)
typedef float f32x4  __attribute__((ext_vector_type(4)));
typedef unsigned short u16;
typedef unsigned int u32;

#define MFMA16(a, b, c) __builtin_amdgcn_mfma_f32_16x16x32_bf16((a), (b), (c), 0, 0, 0)

static __device__ __forceinline__ u16 f2b(float f) {
  __hip_bfloat16 h = __float2bfloat16(f);   // RNE
  return __builtin_bit_cast(u16, h);
}
static __device__ __forceinline__ float b2f(u16 v) {
  unsigned int u = ((unsigned int)v) << 16;
  return __builtin_bit_cast(float, u);
}
static __device__ __forceinline__ u32 pk2(float a, float b) {
  return (u32)f2b(a) | ((u32)f2b(b) << 16);
}

union FragU { uint4 u; bf16x8 v; };

// g-group shuffle: source lane (c,gs) holds (tile t: x=16t+4*gs+r, y=c) packed
// as uint2 {pk2(r0,r1), pk2(r2,r3)} for tiles lo (x 0..15) and hi (x 16..31).
// Returns frag: lane (c,g) elem e = M[x=8g+e][y=c]  (e=0..7).
static __device__ __forceinline__ bf16x8 shufx(uint2 lo, uint2 hi,
                                               int sA4, int sB4, bool uh) {
  u32 l0 = (u32)__builtin_amdgcn_ds_bpermute(sA4, (int)lo.x);
  u32 l1 = (u32)__builtin_amdgcn_ds_bpermute(sA4, (int)lo.y);
  u32 h0 = (u32)__builtin_amdgcn_ds_bpermute(sA4, (int)hi.x);
  u32 h1 = (u32)__builtin_amdgcn_ds_bpermute(sA4, (int)hi.y);
  u32 l2 = (u32)__builtin_amdgcn_ds_bpermute(sB4, (int)lo.x);
  u32 l3 = (u32)__builtin_amdgcn_ds_bpermute(sB4, (int)lo.y);
  u32 h2 = (u32)__builtin_amdgcn_ds_bpermute(sB4, (int)hi.x);
  u32 h3 = (u32)__builtin_amdgcn_ds_bpermute(sB4, (int)hi.y);
  FragU f;
  f.u.x = uh ? h0 : l0;  f.u.y = uh ? h1 : l1;
  f.u.z = uh ? h2 : l2;  f.u.w = uh ? h3 : l3;
  return f.v;
}

// ---------------------------------------------------------------------------
// Prep: b 0..127:   wqkT[o][i] = wqkv[i][o] (o<256 scaled by 32^-0.5) [512][256]
//       b 128..191: wvB  frag-packed Wv[k][col]                       65536 u16
//       b 192..255: woutB frag-packed Wout[k][col]                    65536 u16
//       b 256..259: biasQ[i][j] = bias(query i, key j), bf16          4096 u16
__global__ void prep(const float* __restrict__ wqkv, const float* __restrict__ wout,
                     const float* __restrict__ pos, u16* __restrict__ wqkT,
                     u16* __restrict__ wvB, u16* __restrict__ woutB,
                     u16* __restrict__ biasQ) {
  const int b = blockIdx.x, t = threadIdx.x;
  const float s = 0.17677669529663689f;   // 32^-0.5 folded into Wq
  if (b < 128) {
    int e0 = b * 1024 + t * 4;
#pragma unroll
    for (int i = 0; i < 4; ++i) {
      int e = e0 + i, o = e >> 8, ii = e & 255;
      float v = wqkv[(size_t)ii * 768 + o];
      wqkT[e] = f2b(o < 256 ? v * s : v);
    }
  } else if (b < 192) {
    int e0 = (b - 128) * 1024 + t * 4;
#pragma unroll
    for (int i = 0; i < 4; ++i) {
      int e = e0 + i, frag = e >> 9, w = e & 511, lane = w >> 3, ee = w & 7;
      int k8 = frag >> 4, np = frag & 15;
      int k = k8 * 32 + ((lane >> 4) << 3) + ee;
      int col = 512 + np * 16 + (lane & 15);
      wvB[e] = f2b(wqkv[(size_t)k * 768 + col]);
    }
  } else if (b < 256) {
    int e0 = (b - 192) * 1024 + t * 4;
#pragma unroll
    for (int i = 0; i < 4; ++i) {
      int e = e0 + i, frag = e >> 9, w = e & 511, lane = w >> 3, ee = w & 7;
      int k8 = frag >> 4, np = frag & 15;
      int k = k8 * 32 + ((lane >> 4) << 3) + ee;
      int col = np * 16 + (lane & 15);
      woutB[e] = f2b(wout[(size_t)k * 256 + col]);
    }
  } else {
    int e0 = (b - 256) * 1024 + t * 4;
#pragma unroll
    for (int i = 0; i < 4; ++i) {
      int e = e0 + i, iq = e >> 6, jk = e & 63;
      int ix = iq >> 3, iy = iq & 7, jx = jk >> 3, jy = jk & 7;
      biasQ[e] = f2b(pos[(jx - ix + 7) * 15 + (jy - iy + 7)]);
    }
  }
}

// ---------------------------------------------------------------------------
// Fused window attention: 1 block = 1 window, 8 waves, wave = head.
// Q/K register-resident via operand-swap mfma + bpermute; V^T through LDS
// (wave-private rows: no barrier); bias via bf16 table fed as MFMA C-input.
// r6 structure (best measured: 139.97 us) + s_setprio around attention (T5).
__global__ __launch_bounds__(512, 4)
void winattn(const float* __restrict__ x,
             const u16* __restrict__ wqkT,    // [512][256] bf16 (Q rows scaled)
             const u16* __restrict__ wvB,     // frag-packed [8][16][64][8]
             const u16* __restrict__ woutB,   // frag-packed [8][16][64][8]
             const float* __restrict__ b_out, // [256] f32
             const u16* __restrict__ biasQ,   // [64][64] bf16, query-major
             float* __restrict__ out) {
  __shared__ u16 Xs[64][264];    // bf16 X tile; becomes AO after barrier 2
  __shared__ u16 VTs[256][72];   // V^T[inner][tok], wave-private rows
  __shared__ u16 Bs[64][68];     // bias, query-major bf16

  const int tid  = threadIdx.x;
  const int lane = tid & 63;
  const int h    = tid >> 6;     // wave = head, 0..7
  const int c    = lane & 15;
  const int g    = lane >> 4;

  const int win = blockIdx.x;
  const int img = win >> 8;
  const int wid = win & 255;
  const int py0 = (wid >> 4) << 3;
  const int px0 = (wid & 15) << 3;
  const size_t imgbase = (size_t)img * (128 * 128);

  const f32x4 fz = {0.f, 0.f, 0.f, 0.f};

  // ---- stage X (f32 -> bf16) and bias table
#pragma unroll
  for (int it = 0; it < 8; ++it) {
    int ch = tid + it * 512;            // 4096 = 64 rows x 64 float4
    int row = ch >> 6, c4 = (ch & 63) << 2;
    int py = py0 + (row >> 3), px = px0 + (row & 7);
    const float4 v = *reinterpret_cast<const float4*>(
        x + ((size_t)(imgbase + py * 128 + px)) * 256 + c4);
    ushort4 pk{f2b(v.x), f2b(v.y), f2b(v.z), f2b(v.w)};
    *reinterpret_cast<ushort4*>(&Xs[row][c4]) = pk;
  }
  {   // 4096 u16 bias: each thread two ushort4
    int row = tid >> 3, c0 = (tid & 7) * 8;
    *reinterpret_cast<ushort4*>(&Bs[row][c0]) =
        *reinterpret_cast<const ushort4*>(biasQ + row * 64 + c0);
    *reinterpret_cast<ushort4*>(&Bs[row][c0 + 4]) =
        *reinterpret_cast<const ushort4*>(biasQ + row * 64 + c0 + 4);
  }
  __syncthreads();

  // bpermute lane addresses (loop-invariant)
  const int sA4 = (c + 16 * ((2 * g) & 3)) * 4;
  const int sB4 = (c + 16 * ((2 * g + 1) & 3)) * 4;
  const bool uh = g >= 2;

  const int hq = h * 32, hk = 256 + h * 32;

  // ---- Q pass: Q^T = Wq^T X^T (A=W frag, B=X^T frag) -> qf (B-frags for S^T)
  bf16x8 qf[4];
  {
    f32x4 aq[2][4];
#pragma unroll
    for (int mt = 0; mt < 2; ++mt)
#pragma unroll
      for (int nt = 0; nt < 4; ++nt) aq[mt][nt] = fz;
#pragma unroll 2
    for (int k8 = 0; k8 < 8; ++k8) {
      bf16x8 xb[4];
#pragma unroll
      for (int nt = 0; nt < 4; ++nt)
        xb[nt] = *reinterpret_cast<const bf16x8*>(&Xs[nt * 16 + c][k8 * 32 + g * 8]);
      bf16x8 wq[2];
#pragma unroll
      for (int mt = 0; mt < 2; ++mt)
        wq[mt] = *reinterpret_cast<const bf16x8*>(
            wqkT + (size_t)(hq + mt * 16 + c) * 256 + k8 * 32 + g * 8);
#pragma unroll
      for (int mt = 0; mt < 2; ++mt)
#pragma unroll
        for (int nt = 0; nt < 4; ++nt)
          aq[mt][nt] = MFMA16(wq[mt], xb[nt], aq[mt][nt]);
    }
#pragma unroll
    for (int t4 = 0; t4 < 4; ++t4) {
      uint2 lo{pk2(aq[0][t4][0], aq[0][t4][1]), pk2(aq[0][t4][2], aq[0][t4][3])};
      uint2 hi{pk2(aq[1][t4][0], aq[1][t4][1]), pk2(aq[1][t4][2], aq[1][t4][3])};
      qf[t4] = shufx(lo, hi, sA4, sB4, uh);
    }
  }

  // ---- K pass: K^T = Wk^T X^T -> kf (A-frags for S^T)
  bf16x8 kf[4];
  {
    f32x4 ak[2][4];
#pragma unroll
    for (int mt = 0; mt < 2; ++mt)
#pragma unroll
      for (int nt = 0; nt < 4; ++nt) ak[mt][nt] = fz;
#pragma unroll 2
    for (int k8 = 0; k8 < 8; ++k8) {
      bf16x8 xb[4];
#pragma unroll
      for (int nt = 0; nt < 4; ++nt)
        xb[nt] = *reinterpret_cast<const bf16x8*>(&Xs[nt * 16 + c][k8 * 32 + g * 8]);
      bf16x8 wk[2];
#pragma unroll
      for (int mt = 0; mt < 2; ++mt)
        wk[mt] = *reinterpret_cast<const bf16x8*>(
            wqkT + (size_t)(hk + mt * 16 + c) * 256 + k8 * 32 + g * 8);
#pragma unroll
      for (int mt = 0; mt < 2; ++mt)
#pragma unroll
        for (int nt = 0; nt < 4; ++nt)
          ak[mt][nt] = MFMA16(wk[mt], xb[nt], ak[mt][nt]);
    }
#pragma unroll
    for (int t4 = 0; t4 < 4; ++t4) {
      uint2 lo{pk2(ak[0][t4][0], ak[0][t4][1]), pk2(ak[0][t4][2], ak[0][t4][3])};
      uint2 hi{pk2(ak[1][t4][0], ak[1][t4][1]), pk2(ak[1][t4][2], ak[1][t4][3])};
      kf[t4] = shufx(lo, hi, sA4, sB4, uh);
    }
  }

  // ---- V pass: V = X Wv; D lane (c,g)[r] = V[tok=16mt+4g+r][dim=16(2h+j)+c]
  // -> write V^T straight to LDS (own-head rows only; no barrier needed)
  {
    f32x4 av[4][2];
#pragma unroll
    for (int mt = 0; mt < 4; ++mt)
#pragma unroll
      for (int j = 0; j < 2; ++j) av[mt][j] = fz;
#pragma unroll 1
    for (int k8 = 0; k8 < 8; ++k8) {
      bf16x8 xb[4];
#pragma unroll
      for (int mt = 0; mt < 4; ++mt)
        xb[mt] = *reinterpret_cast<const bf16x8*>(&Xs[mt * 16 + c][k8 * 32 + g * 8]);
      bf16x8 bv[2];
#pragma unroll
      for (int j = 0; j < 2; ++j)
        bv[j] = *reinterpret_cast<const bf16x8*>(
            wvB + (size_t)((k8 * 16 + 2 * h + j) * 64 + lane) * 8);
#pragma unroll
      for (int mt = 0; mt < 4; ++mt)
#pragma unroll
        for (int j = 0; j < 2; ++j)
          av[mt][j] = MFMA16(xb[mt], bv[j], av[mt][j]);
    }
#pragma unroll
    for (int j = 0; j < 2; ++j)
#pragma unroll
      for (int mt = 0; mt < 4; ++mt) {
        ushort4 pk{f2b(av[mt][j][0]), f2b(av[mt][j][1]),
                   f2b(av[mt][j][2]), f2b(av[mt][j][3])};
        *reinterpret_cast<ushort4*>(&VTs[(2 * h + j) * 16 + c][mt * 16 + 4 * g]) = pk;
      }
  }

  // vf[kk][dt]: A-frags for PV, read back from own-head VTs rows
  bf16x8 vf[2][2];
#pragma unroll
  for (int kk = 0; kk < 2; ++kk)
#pragma unroll
    for (int dt = 0; dt < 2; ++dt)
      vf[kk][dt] = *reinterpret_cast<const bf16x8*>(
          &VTs[h * 32 + dt * 16 + c][kk * 32 + g * 8]);

  // ---- attention (priority-boosted), tqt-split: S^T (bias as C-input)
  // -> softmax -> PV -> AO
  __builtin_amdgcn_s_setprio(1);
  ushort4 ao[8];
#pragma unroll
  for (int tqt = 0; tqt < 4; ++tqt) {
    f32x4 stq[4];
#pragma unroll
    for (int tkt = 0; tkt < 4; ++tkt) {
      const ushort4 bb = *reinterpret_cast<const ushort4*>(
          &Bs[tqt * 16 + c][tkt * 16 + 4 * g]);
      const f32x4 bf = {b2f(bb.x), b2f(bb.y), b2f(bb.z), b2f(bb.w)};
      stq[tkt] = MFMA16(kf[tkt], qf[tqt], bf);   // bias added free via C
    }
    // tree max (depth 4) + cross-g
    float m0 = fmaxf(fmaxf(stq[0][0], stq[0][1]), fmaxf(stq[0][2], stq[0][3]));
    float m1 = fmaxf(fmaxf(stq[1][0], stq[1][1]), fmaxf(stq[1][2], stq[1][3]));
    float m2 = fmaxf(fmaxf(stq[2][0], stq[2][1]), fmaxf(stq[2][2], stq[2][3]));
    float m3 = fmaxf(fmaxf(stq[3][0], stq[3][1]), fmaxf(stq[3][2], stq[3][3]));
    float mx = fmaxf(fmaxf(m0, m1), fmaxf(m2, m3));
    mx = fmaxf(mx, __shfl_xor(mx, 16));
    mx = fmaxf(mx, __shfl_xor(mx, 32));
    // exp + tree sum (depth 4) + cross-g
#pragma unroll
    for (int tkt = 0; tkt < 4; ++tkt)
#pragma unroll
      for (int r = 0; r < 4; ++r)
        stq[tkt][r] = __expf(stq[tkt][r] - mx);
    float s0 = (stq[0][0] + stq[0][1]) + (stq[0][2] + stq[0][3]);
    float s1 = (stq[1][0] + stq[1][1]) + (stq[1][2] + stq[1][3]);
    float s2 = (stq[2][0] + stq[2][1]) + (stq[2][2] + stq[2][3]);
    float s3 = (stq[3][0] + stq[3][1]) + (stq[3][2] + stq[3][3]);
    float sum = (s0 + s1) + (s2 + s3);
    sum += __shfl_xor(sum, 16);
    sum += __shfl_xor(sum, 32);
    const float rs = 1.0f / sum;   // off the pf critical path (used post-PV)

    f32x4 o0 = fz, o1 = fz;
#pragma unroll
    for (int kk = 0; kk < 2; ++kk) {   // P unnormalized into pf
      uint2 lo{pk2(stq[2 * kk][0], stq[2 * kk][1]),
               pk2(stq[2 * kk][2], stq[2 * kk][3])};
      uint2 hi{pk2(stq[2 * kk + 1][0], stq[2 * kk + 1][1]),
               pk2(stq[2 * kk + 1][2], stq[2 * kk + 1][3])};
      bf16x8 pf = shufx(lo, hi, sA4, sB4, uh);
      o0 = MFMA16(vf[kk][0], pf, o0);
      o1 = MFMA16(vf[kk][1], pf, o1);
    }
    // rs lives in exactly this lane (tq = c + 16*tqt both sides)
    ao[tqt]     = ushort4{f2b(o0[0] * rs), f2b(o0[1] * rs),
                          f2b(o0[2] * rs), f2b(o0[3] * rs)};
    ao[4 + tqt] = ushort4{f2b(o1[0] * rs), f2b(o1[1] * rs),
                          f2b(o1[2] * rs), f2b(o1[3] * rs)};
  }
  __builtin_amdgcn_s_setprio(0);

  __syncthreads();   // all X reads done -> overlay AO onto Xs
#pragma unroll
  for (int dt = 0; dt < 2; ++dt)
#pragma unroll
    for (int tqt = 0; tqt < 4; ++tqt)
      *reinterpret_cast<ushort4*>(&Xs[c + 16 * tqt][h * 32 + 16 * dt + 4 * g]) =
          ao[dt * 4 + tqt];
  __syncthreads();

  // ---- projection: Y = AO Wout + b_out (A=AO frag from LDS, B=woutB frag)
  f32x4 yc[4][2];
#pragma unroll
  for (int mt = 0; mt < 4; ++mt)
#pragma unroll
    for (int jj = 0; jj < 2; ++jj) yc[mt][jj] = fz;
#pragma unroll 2
  for (int k8 = 0; k8 < 8; ++k8) {
    bf16x8 af[4];
#pragma unroll
    for (int mt = 0; mt < 4; ++mt)
      af[mt] = *reinterpret_cast<const bf16x8*>(&Xs[mt * 16 + c][k8 * 32 + g * 8]);
    bf16x8 bw[2];
#pragma unroll
    for (int jj = 0; jj < 2; ++jj) {
      int nt = h * 2 + jj;
      bw[jj] = *reinterpret_cast<const bf16x8*>(
          woutB + (size_t)((k8 * 16 + nt) * 64 + lane) * 8);
    }
#pragma unroll
    for (int mt = 0; mt < 4; ++mt)
#pragma unroll
      for (int jj = 0; jj < 2; ++jj)
        yc[mt][jj] = MFMA16(af[mt], bw[jj], yc[mt][jj]);
  }
#pragma unroll
  for (int jj = 0; jj < 2; ++jj) {
    const int nt = h * 2 + jj;
    const float bo = b_out[nt * 16 + c];
#pragma unroll
    for (int mt = 0; mt < 4; ++mt)
#pragma unroll
      for (int r = 0; r < 4; ++r) {
        int row = mt * 16 + g * 4 + r;
        int py = py0 + (row >> 3), px = px0 + (row & 7);
        out[((size_t)(imgbase + py * 128 + px)) * 256 + nt * 16 + c] =
            yc[mt][jj][r] + bo;
      }
  }
}

// ---------------------------------------------------------------------------
extern "C" void kernel_launch(void* const* d_in, const int* in_sizes, int n_in,
                              void* d_out, int out_size, void* d_ws, size_t ws_size,
                              hipStream_t stream) {
  const float* x    = (const float*)d_in[0];   // [2,4,128,128,256] f32
  const float* wqkv = (const float*)d_in[1];   // [256,768] f32
  const float* wout = (const float*)d_in[2];   // [256,256] f32
  const float* bout = (const float*)d_in[3];   // [256] f32
  const float* pos  = (const float*)d_in[4];   // [15,15] f32
  float* out = (float*)d_out;

  u16* wqkT  = (u16*)d_ws;                     // 512*256 u16 = 256 KiB
  u16* wvB   = wqkT + 512 * 256;               // 65536 u16 = 128 KiB
  u16* woutB = wvB + 65536;                    // 65536 u16 = 128 KiB
  u16* biasQ = woutB + 65536;                  // 4096 u16 = 8 KiB

  prep<<<260, 256, 0, stream>>>(wqkv, wout, pos, wqkT, wvB, woutB, biasQ);
  winattn<<<2048, 512, 0, stream>>>(x, wqkT, wvB, woutB, bout, biasQ, out);
}